// Round 19
// baseline (75.666 us; speedup 1.0000x reference)
//
#include <hip/hip_runtime.h>

// FirstBlockTexture — full-MFMA facet pipeline (16 facets/wave) + CSR gather.
// Round-19 = round-17 (passed, 65.9 µs) with ONE facet change: explicit
// 8-deep BATCH PREFETCH of B-fragments into statically-indexed register
// arrays before each MFMA group (Tnet: 8; GEMM1: 2x8; GEMM2: 4x8).
// Thesis: at 48 VGPR the scheduler keeps ~1-2 of the 64 per-tile ws-frag
// L2 loads in flight -> GEMM sections are serialized L2 round-trips (the
// all-pipes-30% signature; occupancy/frag-location/ILP all proven non-binding
// in r10/r13/r14/r18). +32 transient VGPR, peak ~80-90 < lb(256,5) cap 102,
// residency unchanged. No loop-carried state, static indexing only.

typedef float f32x4 __attribute__((ext_vector_type(4)));
typedef short s16x8 __attribute__((ext_vector_type(8)));
typedef unsigned int u32;

__device__ __forceinline__ short f2bf(float x) {
    union { float f; u32 u; } v; v.f = x;
    u32 r = (v.u + 0x7fffu + ((v.u >> 16) & 1u)) >> 16;   // RNE
    return (short)r;
}

// ---------------- prep (fused with scanA) ----------------
// ws frag table: 56 segments * 64 lanes * 16B = 57344 B
//   seg 0..3  : Wf2f B-frags (nt)   K=9 pad32
//   seg 4..7  : Wmlp B-frags (nt)   K=8 pad32
//   seg 8..23 : Wdw  B-frags (nt2), CBLK-permuted: col o <- 32*(nt2>>1)+2*o+(nt2&1)
//   seg 24..55: Wpw  B-frags (nt*8+kc), ROW-permuted to match (round-6 scheme)
__global__ void prep_scanA(const float* __restrict__ Wf2f, const float* __restrict__ Wmlp,
                           const float* __restrict__ Wdw,  const float* __restrict__ Wpw,
                           s16x8* __restrict__ wsAll,
                           const int* __restrict__ nfc, int* __restrict__ bsum, int NV)
{
    if (blockIdx.x < 14) {
        int gid = blockIdx.x * 256 + threadIdx.x;
        if (gid >= 56 * 64) return;
        int l = gid & 63, seg = gid >> 6;
        int k4 = l >> 4, o = l & 15;
        s16x8 v;
        if (seg < 4) {
#pragma unroll
            for (int j = 0; j < 8; ++j) { int k = k4 * 8 + j; v[j] = (k < 9) ? f2bf(Wf2f[k * 64 + seg * 16 + o]) : (short)0; }
        } else if (seg < 8) {
            int nt = seg - 4;
#pragma unroll
            for (int j = 0; j < 8; ++j) { int k = k4 * 8 + j; v[j] = (k < 8) ? f2bf(Wmlp[k * 64 + nt * 16 + o]) : (short)0; }
        } else if (seg < 24) {
            int nt2 = seg - 8;
            int cblk = nt2 >> 1, d = nt2 & 1;
            int col = 32 * cblk + 2 * o + d;          // round-6 cblk permutation
#pragma unroll
            for (int j = 0; j < 8; ++j) { int k = k4 * 8 + j; v[j] = (k < 27) ? f2bf(Wdw[k * 256 + col]) : (short)0; }
        } else {
            int s = seg - 24, nt = s >> 3, kc = s & 7;
#pragma unroll
            for (int j = 0; j < 8; ++j) {
                int rp = kc * 32 + k4 * 8 + j;        // permuted row index
                int nt2r = rp >> 4, orr = rp & 15;
                int orig = 32 * (nt2r >> 1) + 2 * orr + (nt2r & 1);
                v[j] = f2bf(Wpw[orig * 64 + nt * 16 + o]);
            }
        }
        wsAll[gid] = v;
    } else {
        __shared__ int sd[256];
        int b = blockIdx.x - 14, t = threadIdx.x;
        int v0 = b * 512 + 2 * t;
        int e0 = (v0 < NV) ? nfc[v0] : 0;
        int e1 = (v0 + 1 < NV) ? nfc[v0 + 1] : 0;
        sd[t] = e0 + e1;
        __syncthreads();
        for (int off = 128; off > 0; off >>= 1) {
            if (t < off) sd[t] += sd[t + off];
            __syncthreads();
        }
        if (t == 0) bsum[b] = sd[0];
    }
}

// scanC2: per-block recompute of block offset + local scan (drops scanB).
__global__ void scanC2(const int* __restrict__ nfc, const int* __restrict__ bsum,
                       int* __restrict__ startArr, int NV, int NB)
{
    __shared__ int sb[256];
    __shared__ int sd[256];
    int b = blockIdx.x, t = threadIdx.x;
    sb[t] = (t < b) ? bsum[t] : 0;            // NB<=256
    __syncthreads();
    for (int off = 128; off > 0; off >>= 1) {
        if (t < off) sb[t] += sb[t + off];
        __syncthreads();
    }
    int boffb = sb[0];
    int v0 = b * 512 + 2 * t;
    int e0 = (v0 < NV) ? nfc[v0] : 0;
    int e1 = (v0 + 1 < NV) ? nfc[v0 + 1] : 0;
    int s = e0 + e1;
    sd[t] = s;
    __syncthreads();
    for (int off = 1; off < 256; off <<= 1) {
        int x = (t >= off) ? sd[t - off] : 0;
        __syncthreads();
        sd[t] += x;
        __syncthreads();
    }
    int off0 = boffb + sd[t] - s;
    if (v0 < NV) startArr[v0] = off0;
    if (v0 + 1 < NV) startArr[v0 + 1] = off0 + e0;
}

// ---------------- facet pipeline: r17 body + batch frag prefetch ----------------
// Per-wave 8 KB LDS slice, 3 sequential wave-private phases (no barriers):
//   1) inputs (3456 B) 2) ct tile [16][256] bf16 swizzled (8192 B)
//   3) y tile [16][64] bf16 swizzled (2048 B)
__global__ __launch_bounds__(256, 5) void facet_kernel(
    const float* __restrict__ geo, const float* __restrict__ tex,
    const float* __restrict__ bary, const int* __restrict__ numtex,
    const float* __restrict__ filt,
    const float* __restrict__ bf2f, const float* __restrict__ bmlp,
    const s16x8* __restrict__ wsAll, unsigned short* __restrict__ ybf,
    int NF, int ntiles)
{
    __shared__ char sAll[4][8192];
    const int l   = threadIdx.x & 63;
    const int wid = threadIdx.x >> 6;
    const int tile = blockIdx.x * 4 + wid;
    if (tile >= ntiles) return;
    const int f0 = tile * 16;
    const int o16 = l & 15, k4 = l >> 4;
    char*  sW  = sAll[wid];
    float* sIn = (float*)sW;

    // ---- phase 1: stage inputs (coalesced float4) ----
    if (f0 + 16 <= NF) {
        const float4* b4 = (const float4*)bary + 36 * (size_t)tile;
        const float4* t4 = (const float4*)tex  + 36 * (size_t)tile;
        const float4* g4 = (const float4*)geo  + 32 * (size_t)tile;
        const float4* q4 = (const float4*)filt + 108 * (size_t)tile;
        const float4* n4 = (const float4*)numtex + 4 * (size_t)tile;  // bit-exact int copy
        float4* d4 = (float4*)sIn;
#pragma unroll
        for (int r = 0; r < 4; ++r) {
            int idx = l + r * 64;
            if (idx < 216) {
                float4 v;
                if      (idx < 36)  v = b4[idx];
                else if (idx < 72)  v = t4[idx - 36];
                else if (idx < 104) v = g4[idx - 72];
                else if (idx < 212) v = q4[idx - 104];
                else                v = n4[idx - 212];
                d4[idx] = v;
            }
        }
    } else {
        for (int idx = l; idx < 864; idx += 64) {
            if (idx < 144)       { int i = idx / 9, j = idx % 9;              int f = min(f0 + i, NF - 1); sIn[idx] = bary[9 * (size_t)f + j]; }
            else if (idx < 288)  { int e = idx - 144; int i = e / 9,  j = e % 9;  int f = min(f0 + i, NF - 1); sIn[idx] = tex [9 * (size_t)f + j]; }
            else if (idx < 416)  { int e = idx - 288; int i = e / 8,  g = e % 8;  int f = min(f0 + i, NF - 1); sIn[idx] = geo [8 * (size_t)f + g]; }
            else if (idx < 848)  { int e = idx - 416; int i = e / 27, k = e % 27; int f = min(f0 + i, NF - 1); sIn[idx] = filt[27 * (size_t)f + k]; }
            else                 { int i = idx - 848;                              int f = min(f0 + i, NF - 1); ((int*)sIn)[idx] = numtex[f]; }
        }
    }

    const s16x8* wsF2f = wsAll;
    const s16x8* wsMlp = wsAll + 4 * 64;
    const s16x8* wsWdw = wsAll + 8 * 64;
    const s16x8* wsWpw = wsAll + 24 * 64;
    const f32x4 z4 = {0.f, 0.f, 0.f, 0.f};

    // ---- front end: A-frags + Tnet/Gnet from LDS inputs ----
    const int i = o16;
    const float* bp = sIn + i * 9;
    const float* tp = sIn + 144 + i * 9;
    float Bm[9] = {0.f,0.f,0.f,0.f,0.f,0.f,0.f,0.f,0.f};
#pragma unroll
    for (int t = 0; t < 3; ++t) {
        float b0 = bp[3*t], b1 = bp[3*t+1], b2 = bp[3*t+2];
        float x0 = tp[3*t], x1 = tp[3*t+1], x2 = tp[3*t+2];
        Bm[0] = fmaf(b0, x0, Bm[0]); Bm[1] = fmaf(b0, x1, Bm[1]); Bm[2] = fmaf(b0, x2, Bm[2]);
        Bm[3] = fmaf(b1, x0, Bm[3]); Bm[4] = fmaf(b1, x1, Bm[4]); Bm[5] = fmaf(b1, x2, Bm[5]);
        Bm[6] = fmaf(b2, x0, Bm[6]); Bm[7] = fmaf(b2, x1, Bm[7]); Bm[8] = fmaf(b2, x2, Bm[8]);
    }
    s16x8 aF2f;
    aF2f[0] = f2bf((k4 == 1) ? Bm[8] : Bm[0]);   // k4==1 lane supplies A[k=8]
#pragma unroll
    for (int j = 1; j < 8; ++j) aF2f[j] = f2bf(Bm[j]);

    const float* gp = sIn + 288 + i * 8;
    s16x8 aMlp;
#pragma unroll
    for (int j = 0; j < 8; ++j) aMlp[j] = f2bf(gp[j]);

    const float* fp = sIn + 416 + i * 27 + k4 * 8;
    s16x8 aFlt;
#pragma unroll
    for (int j = 0; j < 8; ++j) {
        int k = k4 * 8 + j;
        aFlt[j] = (k < 27) ? f2bf(fp[j]) : (short)0;
    }

    float invn[4];
#pragma unroll
    for (int t = 0; t < 4; ++t) invn[t] = 1.0f / (float)((const int*)sIn)[848 + 4 * k4 + t];
    float bfo[4], bmo[4];
#pragma unroll
    for (int nt = 0; nt < 4; ++nt) { bfo[nt] = bf2f[nt * 16 + o16]; bmo[nt] = bmlp[nt * 16 + o16]; }

    // ---- Tnet / Gnet (8 frags batch-prefetched) ----
    float tn[4][4], gn[4][4];                // [nt][t], D-layout row m=4k4+t, col nt*16+o16
    {
        s16x8 fT[4], fG[4];
#pragma unroll
        for (int nt = 0; nt < 4; ++nt) { fT[nt] = wsF2f[nt * 64 + l]; fG[nt] = wsMlp[nt * 64 + l]; }
#pragma unroll
        for (int nt = 0; nt < 4; ++nt) {
            f32x4 aT = __builtin_amdgcn_mfma_f32_16x16x32_bf16(aF2f, fT[nt], z4, 0, 0, 0);
            f32x4 aG = __builtin_amdgcn_mfma_f32_16x16x32_bf16(aMlp, fG[nt], z4, 0, 0, 0);
#pragma unroll
            for (int t = 0; t < 4; ++t) {
                bool mv = (f0 + 4 * k4 + t) < NF;
                float tv = fmaxf(fmaf(aT[t], invn[t], bfo[nt]), 0.f);
                float gv = fmaxf(aG[t] + bmo[nt], 0.f);
                tn[nt][t] = mv ? tv : 0.f;
                gn[nt][t] = mv ? gv : 0.f;
            }
        }
    }

    // ---- phase 2 / GEMM1: 2 batches of 8 prefetched Wdw frags ----
#pragma unroll
    for (int h = 0; h < 2; ++h) {
        s16x8 bw[8];
#pragma unroll
        for (int j = 0; j < 8; ++j) bw[j] = wsWdw[(h * 8 + j) * 64 + l];
#pragma unroll
        for (int j = 0; j < 8; ++j) {
            const int nt2 = h * 8 + j;
            f32x4 acc = __builtin_amdgcn_mfma_f32_16x16x32_bf16(aFlt, bw[j], z4, 0, 0, 0);
            const int cblk = nt2 >> 1;
            const int r = nt2 * 16 + o16;
#pragma unroll
            for (int t = 0; t < 4; ++t) {
                float netv = (nt2 < 8) ? tn[cblk][t] : gn[cblk - 4][t];
                float cv = acc[t] * netv;
                const int m = 4 * k4 + t;
                *(short*)(sW + m * 512 + ((r * 2) ^ ((m & 7) << 4))) = f2bf(cv);
            }
        }
    }

    // ---- GEMM2: 4 batches of 8 prefetched Wpw frags (kc pairs) ----
    f32x4 acc2[4] = {z4, z4, z4, z4};
#pragma unroll
    for (int kp = 0; kp < 4; ++kp) {
        s16x8 bw[8];
#pragma unroll
        for (int j = 0; j < 8; ++j) {
            const int nt = j & 3, kc = 2 * kp + (j >> 2);
            bw[j] = wsWpw[(nt * 8 + kc) * 64 + l];
        }
#pragma unroll
        for (int half = 0; half < 2; ++half) {
            const int kc = 2 * kp + half;
            s16x8 a2 = *(const s16x8*)(sW + o16 * 512 + ((kc * 64 + k4 * 16) ^ ((o16 & 7) << 4)));
#pragma unroll
            for (int nt = 0; nt < 4; ++nt)
                acc2[nt] = __builtin_amdgcn_mfma_f32_16x16x32_bf16(a2, bw[half * 4 + nt], acc2[nt], 0, 0, 0);
        }
    }

    // ---- phase 3: y -> bf16 via LDS transpose, coalesced dwordx4 stores ----
#pragma unroll
    for (int nt = 0; nt < 4; ++nt)
#pragma unroll
        for (int t = 0; t < 4; ++t) {
            const int m = 4 * k4 + t;
            const int c = nt * 16 + o16;
            int off = m * 128 + c * 2;
            off ^= ((m & 7) << 4);
            *(short*)(sW + off) = f2bf(acc2[nt][t]);
        }
    {
        char* dst = (char*)(ybf) + (size_t)tile * 2048;   // [16][64] bf16
#pragma unroll
        for (int q = 0; q < 2; ++q) {
            const int L = (l + q * 64) * 16;
            const int m = L >> 7;
            s16x8 v = *(const s16x8*)(sW + (L ^ ((m & 7) << 4)));
            *(s16x8*)(dst + L) = v;
        }
    }
}

// ---------------- CSR gather: mean + bias + relu ----------------
// thread = (vertex, channel-octet); one uint4 (8 bf16 = 16B) per incidence.
__device__ __forceinline__ void acc8(uint4 q, float* a) {
    union { u32 u; float f; } x;
    x.u = q.x << 16;          a[0] += x.f;
    x.u = q.x & 0xffff0000u;  a[1] += x.f;
    x.u = q.y << 16;          a[2] += x.f;
    x.u = q.y & 0xffff0000u;  a[3] += x.f;
    x.u = q.z << 16;          a[4] += x.f;
    x.u = q.z & 0xffff0000u;  a[5] += x.f;
    x.u = q.w << 16;          a[6] += x.f;
    x.u = q.w & 0xffff0000u;  a[7] += x.f;
}

__global__ __launch_bounds__(256) void vertex_kernel(
    const uint4* __restrict__ y4, const int* __restrict__ vt_map,
    const int* __restrict__ startArr, const int* __restrict__ nfc,
    const float* __restrict__ bpw, float* __restrict__ out, int NV)
{
    const int tid = blockIdx.x * 256 + threadIdx.x;
    const int v  = tid >> 3;
    const int c8 = tid & 7;
    if (v >= NV) return;
    const int start = startArr[v];
    const int cnt   = nfc[v];
    float a[8] = {0.f, 0.f, 0.f, 0.f, 0.f, 0.f, 0.f, 0.f};
    int i = 0;
    for (; i + 4 <= cnt; i += 4) {
        const int fa = vt_map[start + i];
        const int fb = vt_map[start + i + 1];
        const int fc = vt_map[start + i + 2];
        const int fd = vt_map[start + i + 3];
        uint4 qa = y4[(size_t)fa * 8 + c8];
        uint4 qb = y4[(size_t)fb * 8 + c8];
        uint4 qc = y4[(size_t)fc * 8 + c8];
        uint4 qd = y4[(size_t)fd * 8 + c8];
        acc8(qa, a); acc8(qb, a); acc8(qc, a); acc8(qd, a);
    }
    for (; i < cnt; ++i) {
        uint4 q = y4[(size_t)vt_map[start + i] * 8 + c8];
        acc8(q, a);
    }
    const float inv = 1.0f / (float)(cnt > 0 ? cnt : 1);
    const float4 bpa = *(const float4*)(bpw + 8 * c8);
    const float4 bpb = *(const float4*)(bpw + 8 * c8 + 4);
    float4 ra, rb;
    ra.x = fmaxf(fmaf(a[0], inv, bpa.x), 0.f);
    ra.y = fmaxf(fmaf(a[1], inv, bpa.y), 0.f);
    ra.z = fmaxf(fmaf(a[2], inv, bpa.z), 0.f);
    ra.w = fmaxf(fmaf(a[3], inv, bpa.w), 0.f);
    rb.x = fmaxf(fmaf(a[4], inv, bpb.x), 0.f);
    rb.y = fmaxf(fmaf(a[5], inv, bpb.y), 0.f);
    rb.z = fmaxf(fmaf(a[6], inv, bpb.z), 0.f);
    rb.w = fmaxf(fmaf(a[7], inv, bpb.w), 0.f);
    float* op = out + (size_t)v * 64 + 8 * c8;
    *(float4*)op = ra;
    *(float4*)(op + 4) = rb;
}

extern "C" void kernel_launch(void* const* d_in, const int* in_sizes, int n_in,
                              void* d_out, int out_size, void* d_ws, size_t ws_size,
                              hipStream_t stream)
{
    const float* geo    = (const float*)d_in[0];   // [NF,8]
    const float* tex    = (const float*)d_in[1];   // [T,3]
    const float* bary   = (const float*)d_in[2];   // [T,3]
    const int*   numtex = (const int*)  d_in[3];   // [NF]
    const int*   nfc    = (const int*)  d_in[5];   // [NV]
    const int*   vtmap  = (const int*)  d_in[6];   // [3*NF]
    const float* filt   = (const float*)d_in[7];   // [NF,27]
    const float* Wf2f   = (const float*)d_in[8];   // [9,64]
    const float* bf2f   = (const float*)d_in[9];   // [64]
    const float* Wmlp   = (const float*)d_in[10];  // [8,64]
    const float* bmlp   = (const float*)d_in[11];  // [64]
    const float* Wdw    = (const float*)d_in[12];  // [27,128,2]
    const float* Wpw    = (const float*)d_in[13];  // [256,64]
    const float* bpw    = (const float*)d_in[14];  // [64]
    float* out = (float*)d_out;

    const int NF = in_sizes[0] / 8;
    const int NV = in_sizes[5];
    const int ntiles = (NF + 15) / 16;
    const int NB = (NV + 511) / 512;               // <=256 for NV<=131072

    // ws layout
    const size_t offFrag  = 0;                                   // 57344 B
    const size_t offY     = 57344;                               // ntiles*2048 B (bf16 y)
    const size_t offStart = offY + (size_t)ntiles * 2048;
    const size_t offBsum  = offStart + (((size_t)NV * 4 + 255) & ~(size_t)255);

    s16x8*          wsAll    = (s16x8*)((char*)d_ws + offFrag);
    unsigned short* ybf      = (unsigned short*)((char*)d_ws + offY);
    int*            startArr = (int*)((char*)d_ws + offStart);
    int*            bsum     = (int*)((char*)d_ws + offBsum);

    hipLaunchKernelGGL(prep_scanA, dim3(14 + NB), dim3(256), 0, stream,
                       Wf2f, Wmlp, Wdw, Wpw, wsAll, nfc, bsum, NV);
    hipLaunchKernelGGL(scanC2, dim3(NB), dim3(256), 0, stream,
                       nfc, bsum, startArr, NV, NB);

    hipLaunchKernelGGL(facet_kernel, dim3((ntiles + 3) / 4), dim3(256), 0, stream,
                       geo, tex, bary, numtex, filt, bf2f, bmlp, wsAll, ybf, NF, ntiles);

    const int vthreads = NV * 8;
    hipLaunchKernelGGL(vertex_kernel, dim3((vthreads + 255) / 256), dim3(256), 0, stream,
                       (const uint4*)ybf, vtmap, startArr, nfc, bpw, out, NV);
}

// Round 20
// 65.201 us; speedup vs baseline: 1.1605x; 1.1605x over previous
//
#include <hip/hip_runtime.h>

// FirstBlockTexture — full-MFMA facet pipeline (16 facets/wave) + CSR gather.
// Round-20 = round-19 with ONE number changed: facet __launch_bounds__(256,2)
// (was (256,5)). r19's lb(256,5) made the allocator hold 48 VGPR and spill
// the 8-deep frag-prefetch arrays to scratch (WRITE 25->71 MB) — the thesis
// was never tested. lb(256,2) caps at 256 VGPR; r18 proved 88 VGPR no-spill
// at this bound, r14 proved low occupancy costs nothing. This is the clean
// frag-load-depth experiment: 8 B-frag loads in flight per MFMA group.

typedef float f32x4 __attribute__((ext_vector_type(4)));
typedef short s16x8 __attribute__((ext_vector_type(8)));
typedef unsigned int u32;

__device__ __forceinline__ short f2bf(float x) {
    union { float f; u32 u; } v; v.f = x;
    u32 r = (v.u + 0x7fffu + ((v.u >> 16) & 1u)) >> 16;   // RNE
    return (short)r;
}

// ---------------- prep (fused with scanA) ----------------
// ws frag table: 56 segments * 64 lanes * 16B = 57344 B
//   seg 0..3  : Wf2f B-frags (nt)   K=9 pad32
//   seg 4..7  : Wmlp B-frags (nt)   K=8 pad32
//   seg 8..23 : Wdw  B-frags (nt2), CBLK-permuted: col o <- 32*(nt2>>1)+2*o+(nt2&1)
//   seg 24..55: Wpw  B-frags (nt*8+kc), ROW-permuted to match (round-6 scheme)
__global__ void prep_scanA(const float* __restrict__ Wf2f, const float* __restrict__ Wmlp,
                           const float* __restrict__ Wdw,  const float* __restrict__ Wpw,
                           s16x8* __restrict__ wsAll,
                           const int* __restrict__ nfc, int* __restrict__ bsum, int NV)
{
    if (blockIdx.x < 14) {
        int gid = blockIdx.x * 256 + threadIdx.x;
        if (gid >= 56 * 64) return;
        int l = gid & 63, seg = gid >> 6;
        int k4 = l >> 4, o = l & 15;
        s16x8 v;
        if (seg < 4) {
#pragma unroll
            for (int j = 0; j < 8; ++j) { int k = k4 * 8 + j; v[j] = (k < 9) ? f2bf(Wf2f[k * 64 + seg * 16 + o]) : (short)0; }
        } else if (seg < 8) {
            int nt = seg - 4;
#pragma unroll
            for (int j = 0; j < 8; ++j) { int k = k4 * 8 + j; v[j] = (k < 8) ? f2bf(Wmlp[k * 64 + nt * 16 + o]) : (short)0; }
        } else if (seg < 24) {
            int nt2 = seg - 8;
            int cblk = nt2 >> 1, d = nt2 & 1;
            int col = 32 * cblk + 2 * o + d;          // round-6 cblk permutation
#pragma unroll
            for (int j = 0; j < 8; ++j) { int k = k4 * 8 + j; v[j] = (k < 27) ? f2bf(Wdw[k * 256 + col]) : (short)0; }
        } else {
            int s = seg - 24, nt = s >> 3, kc = s & 7;
#pragma unroll
            for (int j = 0; j < 8; ++j) {
                int rp = kc * 32 + k4 * 8 + j;        // permuted row index
                int nt2r = rp >> 4, orr = rp & 15;
                int orig = 32 * (nt2r >> 1) + 2 * orr + (nt2r & 1);
                v[j] = f2bf(Wpw[orig * 64 + nt * 16 + o]);
            }
        }
        wsAll[gid] = v;
    } else {
        __shared__ int sd[256];
        int b = blockIdx.x - 14, t = threadIdx.x;
        int v0 = b * 512 + 2 * t;
        int e0 = (v0 < NV) ? nfc[v0] : 0;
        int e1 = (v0 + 1 < NV) ? nfc[v0 + 1] : 0;
        sd[t] = e0 + e1;
        __syncthreads();
        for (int off = 128; off > 0; off >>= 1) {
            if (t < off) sd[t] += sd[t + off];
            __syncthreads();
        }
        if (t == 0) bsum[b] = sd[0];
    }
}

// scanC2: per-block recompute of block offset + local scan (drops scanB).
__global__ void scanC2(const int* __restrict__ nfc, const int* __restrict__ bsum,
                       int* __restrict__ startArr, int NV, int NB)
{
    __shared__ int sb[256];
    __shared__ int sd[256];
    int b = blockIdx.x, t = threadIdx.x;
    sb[t] = (t < b) ? bsum[t] : 0;            // NB<=256
    __syncthreads();
    for (int off = 128; off > 0; off >>= 1) {
        if (t < off) sb[t] += sb[t + off];
        __syncthreads();
    }
    int boffb = sb[0];
    int v0 = b * 512 + 2 * t;
    int e0 = (v0 < NV) ? nfc[v0] : 0;
    int e1 = (v0 + 1 < NV) ? nfc[v0 + 1] : 0;
    int s = e0 + e1;
    sd[t] = s;
    __syncthreads();
    for (int off = 1; off < 256; off <<= 1) {
        int x = (t >= off) ? sd[t - off] : 0;
        __syncthreads();
        sd[t] += x;
        __syncthreads();
    }
    int off0 = boffb + sd[t] - s;
    if (v0 < NV) startArr[v0] = off0;
    if (v0 + 1 < NV) startArr[v0 + 1] = off0 + e0;
}

// ---------------- facet pipeline: r17 body + batch frag prefetch ----------------
// Per-wave 8 KB LDS slice, 3 sequential wave-private phases (no barriers):
//   1) inputs (3456 B) 2) ct tile [16][256] bf16 swizzled (8192 B)
//   3) y tile [16][64] bf16 swizzled (2048 B)
__global__ __launch_bounds__(256, 2) void facet_kernel(
    const float* __restrict__ geo, const float* __restrict__ tex,
    const float* __restrict__ bary, const int* __restrict__ numtex,
    const float* __restrict__ filt,
    const float* __restrict__ bf2f, const float* __restrict__ bmlp,
    const s16x8* __restrict__ wsAll, unsigned short* __restrict__ ybf,
    int NF, int ntiles)
{
    __shared__ char sAll[4][8192];
    const int l   = threadIdx.x & 63;
    const int wid = threadIdx.x >> 6;
    const int tile = blockIdx.x * 4 + wid;
    if (tile >= ntiles) return;
    const int f0 = tile * 16;
    const int o16 = l & 15, k4 = l >> 4;
    char*  sW  = sAll[wid];
    float* sIn = (float*)sW;

    // ---- phase 1: stage inputs (coalesced float4) ----
    if (f0 + 16 <= NF) {
        const float4* b4 = (const float4*)bary + 36 * (size_t)tile;
        const float4* t4 = (const float4*)tex  + 36 * (size_t)tile;
        const float4* g4 = (const float4*)geo  + 32 * (size_t)tile;
        const float4* q4 = (const float4*)filt + 108 * (size_t)tile;
        const float4* n4 = (const float4*)numtex + 4 * (size_t)tile;  // bit-exact int copy
        float4* d4 = (float4*)sIn;
#pragma unroll
        for (int r = 0; r < 4; ++r) {
            int idx = l + r * 64;
            if (idx < 216) {
                float4 v;
                if      (idx < 36)  v = b4[idx];
                else if (idx < 72)  v = t4[idx - 36];
                else if (idx < 104) v = g4[idx - 72];
                else if (idx < 212) v = q4[idx - 104];
                else                v = n4[idx - 212];
                d4[idx] = v;
            }
        }
    } else {
        for (int idx = l; idx < 864; idx += 64) {
            if (idx < 144)       { int i = idx / 9, j = idx % 9;              int f = min(f0 + i, NF - 1); sIn[idx] = bary[9 * (size_t)f + j]; }
            else if (idx < 288)  { int e = idx - 144; int i = e / 9,  j = e % 9;  int f = min(f0 + i, NF - 1); sIn[idx] = tex [9 * (size_t)f + j]; }
            else if (idx < 416)  { int e = idx - 288; int i = e / 8,  g = e % 8;  int f = min(f0 + i, NF - 1); sIn[idx] = geo [8 * (size_t)f + g]; }
            else if (idx < 848)  { int e = idx - 416; int i = e / 27, k = e % 27; int f = min(f0 + i, NF - 1); sIn[idx] = filt[27 * (size_t)f + k]; }
            else                 { int i = idx - 848;                              int f = min(f0 + i, NF - 1); ((int*)sIn)[idx] = numtex[f]; }
        }
    }

    const s16x8* wsF2f = wsAll;
    const s16x8* wsMlp = wsAll + 4 * 64;
    const s16x8* wsWdw = wsAll + 8 * 64;
    const s16x8* wsWpw = wsAll + 24 * 64;
    const f32x4 z4 = {0.f, 0.f, 0.f, 0.f};

    // ---- front end: A-frags + Tnet/Gnet from LDS inputs ----
    const int i = o16;
    const float* bp = sIn + i * 9;
    const float* tp = sIn + 144 + i * 9;
    float Bm[9] = {0.f,0.f,0.f,0.f,0.f,0.f,0.f,0.f,0.f};
#pragma unroll
    for (int t = 0; t < 3; ++t) {
        float b0 = bp[3*t], b1 = bp[3*t+1], b2 = bp[3*t+2];
        float x0 = tp[3*t], x1 = tp[3*t+1], x2 = tp[3*t+2];
        Bm[0] = fmaf(b0, x0, Bm[0]); Bm[1] = fmaf(b0, x1, Bm[1]); Bm[2] = fmaf(b0, x2, Bm[2]);
        Bm[3] = fmaf(b1, x0, Bm[3]); Bm[4] = fmaf(b1, x1, Bm[4]); Bm[5] = fmaf(b1, x2, Bm[5]);
        Bm[6] = fmaf(b2, x0, Bm[6]); Bm[7] = fmaf(b2, x1, Bm[7]); Bm[8] = fmaf(b2, x2, Bm[8]);
    }
    s16x8 aF2f;
    aF2f[0] = f2bf((k4 == 1) ? Bm[8] : Bm[0]);   // k4==1 lane supplies A[k=8]
#pragma unroll
    for (int j = 1; j < 8; ++j) aF2f[j] = f2bf(Bm[j]);

    const float* gp = sIn + 288 + i * 8;
    s16x8 aMlp;
#pragma unroll
    for (int j = 0; j < 8; ++j) aMlp[j] = f2bf(gp[j]);

    const float* fp = sIn + 416 + i * 27 + k4 * 8;
    s16x8 aFlt;
#pragma unroll
    for (int j = 0; j < 8; ++j) {
        int k = k4 * 8 + j;
        aFlt[j] = (k < 27) ? f2bf(fp[j]) : (short)0;
    }

    float invn[4];
#pragma unroll
    for (int t = 0; t < 4; ++t) invn[t] = 1.0f / (float)((const int*)sIn)[848 + 4 * k4 + t];
    float bfo[4], bmo[4];
#pragma unroll
    for (int nt = 0; nt < 4; ++nt) { bfo[nt] = bf2f[nt * 16 + o16]; bmo[nt] = bmlp[nt * 16 + o16]; }

    // ---- Tnet / Gnet (8 frags batch-prefetched) ----
    float tn[4][4], gn[4][4];                // [nt][t], D-layout row m=4k4+t, col nt*16+o16
    {
        s16x8 fT[4], fG[4];
#pragma unroll
        for (int nt = 0; nt < 4; ++nt) { fT[nt] = wsF2f[nt * 64 + l]; fG[nt] = wsMlp[nt * 64 + l]; }
#pragma unroll
        for (int nt = 0; nt < 4; ++nt) {
            f32x4 aT = __builtin_amdgcn_mfma_f32_16x16x32_bf16(aF2f, fT[nt], z4, 0, 0, 0);
            f32x4 aG = __builtin_amdgcn_mfma_f32_16x16x32_bf16(aMlp, fG[nt], z4, 0, 0, 0);
#pragma unroll
            for (int t = 0; t < 4; ++t) {
                bool mv = (f0 + 4 * k4 + t) < NF;
                float tv = fmaxf(fmaf(aT[t], invn[t], bfo[nt]), 0.f);
                float gv = fmaxf(aG[t] + bmo[nt], 0.f);
                tn[nt][t] = mv ? tv : 0.f;
                gn[nt][t] = mv ? gv : 0.f;
            }
        }
    }

    // ---- phase 2 / GEMM1: 2 batches of 8 prefetched Wdw frags ----
#pragma unroll
    for (int h = 0; h < 2; ++h) {
        s16x8 bw[8];
#pragma unroll
        for (int j = 0; j < 8; ++j) bw[j] = wsWdw[(h * 8 + j) * 64 + l];
#pragma unroll
        for (int j = 0; j < 8; ++j) {
            const int nt2 = h * 8 + j;
            f32x4 acc = __builtin_amdgcn_mfma_f32_16x16x32_bf16(aFlt, bw[j], z4, 0, 0, 0);
            const int cblk = nt2 >> 1;
            const int r = nt2 * 16 + o16;
#pragma unroll
            for (int t = 0; t < 4; ++t) {
                float netv = (nt2 < 8) ? tn[cblk][t] : gn[cblk - 4][t];
                float cv = acc[t] * netv;
                const int m = 4 * k4 + t;
                *(short*)(sW + m * 512 + ((r * 2) ^ ((m & 7) << 4))) = f2bf(cv);
            }
        }
    }

    // ---- GEMM2: 4 batches of 8 prefetched Wpw frags (kc pairs) ----
    f32x4 acc2[4] = {z4, z4, z4, z4};
#pragma unroll
    for (int kp = 0; kp < 4; ++kp) {
        s16x8 bw[8];
#pragma unroll
        for (int j = 0; j < 8; ++j) {
            const int nt = j & 3, kc = 2 * kp + (j >> 2);
            bw[j] = wsWpw[(nt * 8 + kc) * 64 + l];
        }
#pragma unroll
        for (int half = 0; half < 2; ++half) {
            const int kc = 2 * kp + half;
            s16x8 a2 = *(const s16x8*)(sW + o16 * 512 + ((kc * 64 + k4 * 16) ^ ((o16 & 7) << 4)));
#pragma unroll
            for (int nt = 0; nt < 4; ++nt)
                acc2[nt] = __builtin_amdgcn_mfma_f32_16x16x32_bf16(a2, bw[half * 4 + nt], acc2[nt], 0, 0, 0);
        }
    }

    // ---- phase 3: y -> bf16 via LDS transpose, coalesced dwordx4 stores ----
#pragma unroll
    for (int nt = 0; nt < 4; ++nt)
#pragma unroll
        for (int t = 0; t < 4; ++t) {
            const int m = 4 * k4 + t;
            const int c = nt * 16 + o16;
            int off = m * 128 + c * 2;
            off ^= ((m & 7) << 4);
            *(short*)(sW + off) = f2bf(acc2[nt][t]);
        }
    {
        char* dst = (char*)(ybf) + (size_t)tile * 2048;   // [16][64] bf16
#pragma unroll
        for (int q = 0; q < 2; ++q) {
            const int L = (l + q * 64) * 16;
            const int m = L >> 7;
            s16x8 v = *(const s16x8*)(sW + (L ^ ((m & 7) << 4)));
            *(s16x8*)(dst + L) = v;
        }
    }
}

// ---------------- CSR gather: mean + bias + relu ----------------
// thread = (vertex, channel-octet); one uint4 (8 bf16 = 16B) per incidence.
__device__ __forceinline__ void acc8(uint4 q, float* a) {
    union { u32 u; float f; } x;
    x.u = q.x << 16;          a[0] += x.f;
    x.u = q.x & 0xffff0000u;  a[1] += x.f;
    x.u = q.y << 16;          a[2] += x.f;
    x.u = q.y & 0xffff0000u;  a[3] += x.f;
    x.u = q.z << 16;          a[4] += x.f;
    x.u = q.z & 0xffff0000u;  a[5] += x.f;
    x.u = q.w << 16;          a[6] += x.f;
    x.u = q.w & 0xffff0000u;  a[7] += x.f;
}

__global__ __launch_bounds__(256) void vertex_kernel(
    const uint4* __restrict__ y4, const int* __restrict__ vt_map,
    const int* __restrict__ startArr, const int* __restrict__ nfc,
    const float* __restrict__ bpw, float* __restrict__ out, int NV)
{
    const int tid = blockIdx.x * 256 + threadIdx.x;
    const int v  = tid >> 3;
    const int c8 = tid & 7;
    if (v >= NV) return;
    const int start = startArr[v];
    const int cnt   = nfc[v];
    float a[8] = {0.f, 0.f, 0.f, 0.f, 0.f, 0.f, 0.f, 0.f};
    int i = 0;
    for (; i + 4 <= cnt; i += 4) {
        const int fa = vt_map[start + i];
        const int fb = vt_map[start + i + 1];
        const int fc = vt_map[start + i + 2];
        const int fd = vt_map[start + i + 3];
        uint4 qa = y4[(size_t)fa * 8 + c8];
        uint4 qb = y4[(size_t)fb * 8 + c8];
        uint4 qc = y4[(size_t)fc * 8 + c8];
        uint4 qd = y4[(size_t)fd * 8 + c8];
        acc8(qa, a); acc8(qb, a); acc8(qc, a); acc8(qd, a);
    }
    for (; i < cnt; ++i) {
        uint4 q = y4[(size_t)vt_map[start + i] * 8 + c8];
        acc8(q, a);
    }
    const float inv = 1.0f / (float)(cnt > 0 ? cnt : 1);
    const float4 bpa = *(const float4*)(bpw + 8 * c8);
    const float4 bpb = *(const float4*)(bpw + 8 * c8 + 4);
    float4 ra, rb;
    ra.x = fmaxf(fmaf(a[0], inv, bpa.x), 0.f);
    ra.y = fmaxf(fmaf(a[1], inv, bpa.y), 0.f);
    ra.z = fmaxf(fmaf(a[2], inv, bpa.z), 0.f);
    ra.w = fmaxf(fmaf(a[3], inv, bpa.w), 0.f);
    rb.x = fmaxf(fmaf(a[4], inv, bpb.x), 0.f);
    rb.y = fmaxf(fmaf(a[5], inv, bpb.y), 0.f);
    rb.z = fmaxf(fmaf(a[6], inv, bpb.z), 0.f);
    rb.w = fmaxf(fmaf(a[7], inv, bpb.w), 0.f);
    float* op = out + (size_t)v * 64 + 8 * c8;
    *(float4*)op = ra;
    *(float4*)(op + 4) = rb;
}

extern "C" void kernel_launch(void* const* d_in, const int* in_sizes, int n_in,
                              void* d_out, int out_size, void* d_ws, size_t ws_size,
                              hipStream_t stream)
{
    const float* geo    = (const float*)d_in[0];   // [NF,8]
    const float* tex    = (const float*)d_in[1];   // [T,3]
    const float* bary   = (const float*)d_in[2];   // [T,3]
    const int*   numtex = (const int*)  d_in[3];   // [NF]
    const int*   nfc    = (const int*)  d_in[5];   // [NV]
    const int*   vtmap  = (const int*)  d_in[6];   // [3*NF]
    const float* filt   = (const float*)d_in[7];   // [NF,27]
    const float* Wf2f   = (const float*)d_in[8];   // [9,64]
    const float* bf2f   = (const float*)d_in[9];   // [64]
    const float* Wmlp   = (const float*)d_in[10];  // [8,64]
    const float* bmlp   = (const float*)d_in[11];  // [64]
    const float* Wdw    = (const float*)d_in[12];  // [27,128,2]
    const float* Wpw    = (const float*)d_in[13];  // [256,64]
    const float* bpw    = (const float*)d_in[14];  // [64]
    float* out = (float*)d_out;

    const int NF = in_sizes[0] / 8;
    const int NV = in_sizes[5];
    const int ntiles = (NF + 15) / 16;
    const int NB = (NV + 511) / 512;               // <=256 for NV<=131072

    // ws layout
    const size_t offFrag  = 0;                                   // 57344 B
    const size_t offY     = 57344;                               // ntiles*2048 B (bf16 y)
    const size_t offStart = offY + (size_t)ntiles * 2048;
    const size_t offBsum  = offStart + (((size_t)NV * 4 + 255) & ~(size_t)255);

    s16x8*          wsAll    = (s16x8*)((char*)d_ws + offFrag);
    unsigned short* ybf      = (unsigned short*)((char*)d_ws + offY);
    int*            startArr = (int*)((char*)d_ws + offStart);
    int*            bsum     = (int*)((char*)d_ws + offBsum);

    hipLaunchKernelGGL(prep_scanA, dim3(14 + NB), dim3(256), 0, stream,
                       Wf2f, Wmlp, Wdw, Wpw, wsAll, nfc, bsum, NV);
    hipLaunchKernelGGL(scanC2, dim3(NB), dim3(256), 0, stream,
                       nfc, bsum, startArr, NV, NB);

    hipLaunchKernelGGL(facet_kernel, dim3((ntiles + 3) / 4), dim3(256), 0, stream,
                       geo, tex, bary, numtex, filt, bf2f, bmlp, wsAll, ybf, NF, ntiles);

    const int vthreads = NV * 8;
    hipLaunchKernelGGL(vertex_kernel, dim3((vthreads + 255) / 256), dim3(256), 0, stream,
                       (const uint4*)ybf, vtmap, startArr, nfc, bpw, out, NV);
}